// Round 2
// baseline (792.063 us; speedup 1.0000x reference)
//
#include <hip/hip_runtime.h>

// ---------------------------------------------------------------------------
// Grouped MLP: h1 = x @ W1^T + b1 ; out = h1 @ W2^T + b2, per group g in [0,8)
// x  [8, 2048, 1024] f32    W1 [8, 4096, 1024] f32   b1 [8, 4096] f32
// W2 [8, 1024, 4096] f32    b2 [8, 1024] f32         out [8, 2048, 1024] f32
//
// R2: XCD-aware 1D block swizzle (g = bid & 7 -> one group per XCD via the
// round-robin dispatch heuristic; m-inner for GEMM1 so the 4.2 MB per-group
// A stays L2-resident; n-inner for GEMM2). Converts merged into one launch.
// ---------------------------------------------------------------------------

typedef __bf16 bf16_t;
typedef bf16_t bf16x8 __attribute__((ext_vector_type(8)));
typedef float  floatx4 __attribute__((ext_vector_type(4)));

#define NUM_GEMMS 8
#define HIDDEN 1024
#define INTER 4096
#define MTOK 2048

__device__ __forceinline__ void async_copy16(const bf16_t* gsrc, bf16_t* lds_base) {
  // LDS dest is wave-uniform base + lane*16 (HW semantics); pass wave base.
  __builtin_amdgcn_global_load_lds(
      (const __attribute__((address_space(1))) void*)gsrc,
      (__attribute__((address_space(3))) void*)lds_base,
      16, 0, 0);
}

__device__ __forceinline__ void cvt_region(const float* __restrict__ src,
                                           bf16_t* __restrict__ dst,
                                           size_t n8, size_t gid, size_t gstride) {
  const float4* s4 = (const float4*)src;
  for (size_t i = gid; i < n8; i += gstride) {
    float4 a = s4[2 * i];
    float4 b = s4[2 * i + 1];
    bf16x8 o;
    o[0] = (bf16_t)a.x; o[1] = (bf16_t)a.y; o[2] = (bf16_t)a.z; o[3] = (bf16_t)a.w;
    o[4] = (bf16_t)b.x; o[5] = (bf16_t)b.y; o[6] = (bf16_t)b.z; o[7] = (bf16_t)b.w;
    *(bf16x8*)(dst + i * 8) = o;
  }
}

// One launch converts all three fp32 tensors to bf16 (grid-stride).
__global__ __launch_bounds__(256) void cvt3_kernel(
    const float* __restrict__ s0, bf16_t* __restrict__ d0, size_t n8_0,
    const float* __restrict__ s1, bf16_t* __restrict__ d1, size_t n8_1,
    const float* __restrict__ s2, bf16_t* __restrict__ d2, size_t n8_2) {
  const size_t gid = (size_t)blockIdx.x * 256 + threadIdx.x;
  const size_t gstride = (size_t)gridDim.x * 256;
  cvt_region(s0, d0, n8_0, gid, gstride);
  cvt_region(s1, d1, n8_1, gid, gstride);
  cvt_region(s2, d2, n8_2, gid, gstride);
}

// C[g,m,n] = sum_k A[g,m,k] * B[g,n,k] + bias[g,n]
// 128x128 tile, BK=32, 256 threads (4 waves, each 64x64 as 4x4 16x16 frags).
// 1D grid: bid -> (g = bid&7, local = bid>>3); M_INNER picks tile order.
template <int M, int N, int K, bool OUT_BF16, bool M_INNER>
__global__ __launch_bounds__(256) void gemm_bt(const bf16_t* __restrict__ A,
                                               const bf16_t* __restrict__ B,
                                               const float* __restrict__ bias,
                                               void* __restrict__ Cout) {
  constexpr int BM = 128, BN = 128, BK = 32;
  constexpr int MT = M / BM, NT = N / BN;
  __shared__ bf16_t As[BM * BK];  // 8 KB, row-major [row][k], no padding
  __shared__ bf16_t Bs[BN * BK];  // 8 KB (B^T tile: [n][k])

  const unsigned bid   = blockIdx.x;
  const int g          = bid & 7;          // group == XCD (round-robin heuristic)
  const unsigned local = bid >> 3;         // per-group tile index
  int mt, nt;
  if constexpr (M_INNER) { mt = local % MT; nt = local / MT; }
  else                   { nt = local % NT; mt = local / NT; }
  const int m0 = mt * BM;
  const int n0 = nt * BN;

  const bf16_t* Ag = A + (size_t)g * M * K;
  const bf16_t* Bg = B + (size_t)g * N * K;

  const int t    = threadIdx.x;
  const int lane = t & 63;
  const int wave = t >> 6;
  const int wm   = (wave >> 1) * 64;  // wave row offset in C tile
  const int wn   = (wave & 1) * 64;   // wave col offset
  const int l16  = lane & 15;
  const int quad = lane >> 4;

  // Staging map: thread t covers 16B chunk t (rows 0..63) and t+256 (rows 64..127)
  const int sr = t >> 2;
  const int sc = (t & 3) * 8;
  const bf16_t* a0 = Ag + (size_t)(m0 + sr) * K + sc;
  const bf16_t* a1 = a0 + (size_t)64 * K;
  const bf16_t* b0 = Bg + (size_t)(n0 + sr) * K + sc;
  const bf16_t* b1 = b0 + (size_t)64 * K;

  bf16_t* a_lds0 = As + wave * 512;
  bf16_t* a_lds1 = As + wave * 512 + 2048;
  bf16_t* b_lds0 = Bs + wave * 512;
  bf16_t* b_lds1 = Bs + wave * 512 + 2048;

  floatx4 acc[4][4];
  const floatx4 z = {0.0f, 0.0f, 0.0f, 0.0f};
#pragma unroll
  for (int i = 0; i < 4; ++i)
#pragma unroll
    for (int j = 0; j < 4; ++j) acc[i][j] = z;

  for (int kk = 0; kk < K / BK; ++kk) {
    const int kof = kk * BK;
    async_copy16(a0 + kof, a_lds0);
    async_copy16(a1 + kof, a_lds1);
    async_copy16(b0 + kof, b_lds0);
    async_copy16(b1 + kof, b_lds1);
    __syncthreads();  // drains vmcnt (compiler emits full waitcnt before barrier)

    bf16x8 af[4], bfr[4];
#pragma unroll
    for (int i = 0; i < 4; ++i)
      af[i] = *(const bf16x8*)(As + (wm + i * 16 + l16) * BK + quad * 8);
#pragma unroll
    for (int j = 0; j < 4; ++j)
      bfr[j] = *(const bf16x8*)(Bs + (wn + j * 16 + l16) * BK + quad * 8);

#pragma unroll
    for (int i = 0; i < 4; ++i)
#pragma unroll
      for (int j = 0; j < 4; ++j)
        acc[i][j] = __builtin_amdgcn_mfma_f32_16x16x32_bf16(af[i], bfr[j],
                                                            acc[i][j], 0, 0, 0);
    __syncthreads();
  }

  // Epilogue: C/D layout col = lane&15, row = quad*4 + reg (m89/m91 verified)
  const float* bg = bias + (size_t)g * N;
#pragma unroll
  for (int j = 0; j < 4; ++j) {
    const int n  = n0 + wn + j * 16 + l16;
    const float bv = bg[n];
#pragma unroll
    for (int i = 0; i < 4; ++i) {
      const int mr = m0 + wm + i * 16 + quad * 4;
#pragma unroll
      for (int r = 0; r < 4; ++r) {
        const float v = acc[i][j][r] + bv;
        const size_t idx = (size_t)g * M * N + (size_t)(mr + r) * N + n;
        if constexpr (OUT_BF16)
          ((bf16_t*)Cout)[idx] = (bf16_t)v;
        else
          ((float*)Cout)[idx] = v;
      }
    }
  }
}

extern "C" void kernel_launch(void* const* d_in, const int* in_sizes, int n_in,
                              void* d_out, int out_size, void* d_ws, size_t ws_size,
                              hipStream_t stream) {
  const float* x  = (const float*)d_in[0];
  const float* W1 = (const float*)d_in[1];
  const float* b1 = (const float*)d_in[2];
  const float* W2 = (const float*)d_in[3];
  const float* b2 = (const float*)d_in[4];
  float* out = (float*)d_out;

  const size_t nx  = (size_t)NUM_GEMMS * MTOK * HIDDEN;   // 16.7M
  const size_t nw1 = (size_t)NUM_GEMMS * INTER * HIDDEN;  // 33.5M
  const size_t nw2 = nw1;                                 // 33.5M

  // ws layout (bf16): xb | w1b | w2b | h1  => ~302 MB total
  bf16_t* xb  = (bf16_t*)d_ws;
  bf16_t* w1b = xb + nx;
  bf16_t* w2b = w1b + nw1;
  bf16_t* h1  = w2b + nw2;

  cvt3_kernel<<<dim3(2048), dim3(256), 0, stream>>>(
      x, xb, nx / 8, W1, w1b, nw1 / 8, W2, w2b, nw2 / 8);

  // GEMM1: M=2048, N=4096(INTER), K=1024(HIDDEN) -> h1 (bf16)
  // m-inner: 64 resident blocks/XCD span full per-group A (4.2 MB, L2-resident)
  gemm_bt<MTOK, INTER, HIDDEN, true, true>
      <<<dim3(NUM_GEMMS * (MTOK / 128) * (INTER / 128)), dim3(256), 0, stream>>>(
          xb, w1b, b1, (void*)h1);

  // GEMM2: M=2048, N=1024(HIDDEN), K=4096(INTER) -> out (fp32)
  // n-inner: 8 consecutive blocks share one 1 MB h1 A-tile
  gemm_bt<MTOK, HIDDEN, INTER, false, false>
      <<<dim3(NUM_GEMMS * (MTOK / 128) * (HIDDEN / 128)), dim3(256), 0, stream>>>(
          h1, w2b, b2, (void*)out);
}

// Round 3
// 766.224 us; speedup vs baseline: 1.0337x; 1.0337x over previous
//
#include <hip/hip_runtime.h>

// ---------------------------------------------------------------------------
// Grouped MLP: h1 = x @ W1^T + b1 ; out = h1 @ W2^T + b2, per group g in [0,8)
// x  [8, 2048, 1024] f32    W1 [8, 4096, 1024] f32   b1 [8, 4096] f32
// W2 [8, 1024, 4096] f32    b2 [8, 1024] f32         out [8, 2048, 1024] f32
//
// R3: BK=64 (halve barrier-drain count; GEMMs were stall-bound at 15% HBM,
// 22% MfmaUtil) + XOR-swizzled LDS (kills the 1.7e7 bank conflicts; swizzle
// folded into the staging source-column so global_load_lds's wave-uniform
// dest constraint is preserved). XCD swizzle (g = bid&7) kept from R2.
// ---------------------------------------------------------------------------

typedef __bf16 bf16_t;
typedef bf16_t bf16x8 __attribute__((ext_vector_type(8)));
typedef float  floatx4 __attribute__((ext_vector_type(4)));

#define NUM_GEMMS 8
#define HIDDEN 1024
#define INTER 4096
#define MTOK 2048

__device__ __forceinline__ void async_copy16(const bf16_t* gsrc, bf16_t* lds_base) {
  // LDS dest is wave-uniform base + lane*16 (HW semantics); pass wave base.
  __builtin_amdgcn_global_load_lds(
      (const __attribute__((address_space(1))) void*)gsrc,
      (__attribute__((address_space(3))) void*)lds_base,
      16, 0, 0);
}

__device__ __forceinline__ void cvt_region(const float* __restrict__ src,
                                           bf16_t* __restrict__ dst,
                                           size_t n8, size_t gid, size_t gstride) {
  const float4* s4 = (const float4*)src;
  for (size_t i = gid; i < n8; i += gstride) {
    float4 a = s4[2 * i];
    float4 b = s4[2 * i + 1];
    bf16x8 o;
    o[0] = (bf16_t)a.x; o[1] = (bf16_t)a.y; o[2] = (bf16_t)a.z; o[3] = (bf16_t)a.w;
    o[4] = (bf16_t)b.x; o[5] = (bf16_t)b.y; o[6] = (bf16_t)b.z; o[7] = (bf16_t)b.w;
    *(bf16x8*)(dst + i * 8) = o;
  }
}

// One launch converts all three fp32 tensors to bf16 (grid-stride).
__global__ __launch_bounds__(256) void cvt3_kernel(
    const float* __restrict__ s0, bf16_t* __restrict__ d0, size_t n8_0,
    const float* __restrict__ s1, bf16_t* __restrict__ d1, size_t n8_1,
    const float* __restrict__ s2, bf16_t* __restrict__ d2, size_t n8_2) {
  const size_t gid = (size_t)blockIdx.x * 256 + threadIdx.x;
  const size_t gstride = (size_t)gridDim.x * 256;
  cvt_region(s0, d0, n8_0, gid, gstride);
  cvt_region(s1, d1, n8_1, gid, gstride);
  cvt_region(s2, d2, n8_2, gid, gstride);
}

// C[g,m,n] = sum_k A[g,m,k] * B[g,n,k] + bias[g,n]
// 128x128 tile, BK=64, 256 threads (4 waves, each 64x64 as 4x4 16x16 frags).
// LDS layout: logical element (row, k) lives at row*64 + (cb ^ (row&7))*8 + k%8
// where cb = k/8 (16B chunk index). Staging compensates by fetching source
// column ((t&7) ^ ((t>>3)&7))*8 so each lane's fixed LDS slot gets the right
// global chunk. ds_read of chunk cb uses slot cb ^ (row&7) -> conflict-free.
template <int M, int N, int K, bool OUT_BF16, bool M_INNER>
__global__ __launch_bounds__(256) void gemm_bt(const bf16_t* __restrict__ A,
                                               const bf16_t* __restrict__ B,
                                               const float* __restrict__ bias,
                                               void* __restrict__ Cout) {
  constexpr int BM = 128, BN = 128, BK = 64;
  constexpr int MT = M / BM, NT = N / BN;
  __shared__ bf16_t As[BM * BK];  // 16 KB
  __shared__ bf16_t Bs[BN * BK];  // 16 KB

  const unsigned bid   = blockIdx.x;
  const int g          = bid & 7;   // group == XCD (round-robin heuristic)
  const unsigned local = bid >> 3;  // per-group tile index
  int mt, nt;
  if constexpr (M_INNER) { mt = local % MT; nt = local / MT; }
  else                   { nt = local % NT; mt = local / NT; }
  const int m0 = mt * BM;
  const int n0 = nt * BN;

  const bf16_t* Ag = A + (size_t)g * M * K;
  const bf16_t* Bg = B + (size_t)g * N * K;

  const int t    = threadIdx.x;
  const int lane = t & 63;
  const int wave = t >> 6;
  const int wm   = (wave >> 1) * 64;  // wave row offset in C tile
  const int wn   = (wave & 1) * 64;   // wave col offset
  const int l16  = lane & 15;
  const int quad = lane >> 4;

  // Staging: instr q of thread t fills LDS 16B-chunk (q*256 + t).
  // That chunk is row (q*32 + t>>3), stored-col (t&7); under the XOR swizzle
  // its global source column is ((t&7) ^ ((t>>3)&7)) * 8.
  const int sr = t >> 3;                          // 0..31 (row within q-slab)
  const int sc = ((t & 7) ^ ((t >> 3) & 7)) * 8;  // swizzle-compensated col
  const bf16_t* aP0 = Ag + (size_t)(m0 + sr) * K + sc;
  const bf16_t* bP0 = Bg + (size_t)(n0 + sr) * K + sc;

  floatx4 acc[4][4];
  const floatx4 z = {0.0f, 0.0f, 0.0f, 0.0f};
#pragma unroll
  for (int i = 0; i < 4; ++i)
#pragma unroll
    for (int j = 0; j < 4; ++j) acc[i][j] = z;

  for (int kk = 0; kk < K / BK; ++kk) {
    const int kof = kk * BK;
#pragma unroll
    for (int q = 0; q < 4; ++q) {
      async_copy16(aP0 + (size_t)(q * 32) * K + kof, As + wave * 512 + q * 2048);
      async_copy16(bP0 + (size_t)(q * 32) * K + kof, Bs + wave * 512 + q * 2048);
    }
    __syncthreads();  // drains vmcnt (compiler emits full waitcnt before barrier)

#pragma unroll
    for (int ks = 0; ks < 2; ++ks) {
      bf16x8 af[4], bfr[4];
#pragma unroll
      for (int i = 0; i < 4; ++i) {
        const int row = wm + i * 16 + l16;
        af[i] = *(const bf16x8*)(As + row * BK + ((ks * 4 + quad) ^ (row & 7)) * 8);
      }
#pragma unroll
      for (int j = 0; j < 4; ++j) {
        const int row = wn + j * 16 + l16;
        bfr[j] = *(const bf16x8*)(Bs + row * BK + ((ks * 4 + quad) ^ (row & 7)) * 8);
      }
#pragma unroll
      for (int i = 0; i < 4; ++i)
#pragma unroll
        for (int j = 0; j < 4; ++j)
          acc[i][j] = __builtin_amdgcn_mfma_f32_16x16x32_bf16(af[i], bfr[j],
                                                              acc[i][j], 0, 0, 0);
    }
    __syncthreads();
  }

  // Epilogue: C/D layout col = lane&15, row = quad*4 + reg (m89/m91 verified)
  const float* bg = bias + (size_t)g * N;
#pragma unroll
  for (int j = 0; j < 4; ++j) {
    const int n  = n0 + wn + j * 16 + l16;
    const float bv = bg[n];
#pragma unroll
    for (int i = 0; i < 4; ++i) {
      const int mr = m0 + wm + i * 16 + quad * 4;
#pragma unroll
      for (int r = 0; r < 4; ++r) {
        const float v = acc[i][j][r] + bv;
        const size_t idx = (size_t)g * M * N + (size_t)(mr + r) * N + n;
        if constexpr (OUT_BF16)
          ((bf16_t*)Cout)[idx] = (bf16_t)v;
        else
          ((float*)Cout)[idx] = v;
      }
    }
  }
}

extern "C" void kernel_launch(void* const* d_in, const int* in_sizes, int n_in,
                              void* d_out, int out_size, void* d_ws, size_t ws_size,
                              hipStream_t stream) {
  const float* x  = (const float*)d_in[0];
  const float* W1 = (const float*)d_in[1];
  const float* b1 = (const float*)d_in[2];
  const float* W2 = (const float*)d_in[3];
  const float* b2 = (const float*)d_in[4];
  float* out = (float*)d_out;

  const size_t nx  = (size_t)NUM_GEMMS * MTOK * HIDDEN;   // 16.7M
  const size_t nw1 = (size_t)NUM_GEMMS * INTER * HIDDEN;  // 33.5M
  const size_t nw2 = nw1;                                 // 33.5M

  // ws layout (bf16): xb | w1b | w2b | h1  => ~302 MB total
  bf16_t* xb  = (bf16_t*)d_ws;
  bf16_t* w1b = xb + nx;
  bf16_t* w2b = w1b + nw1;
  bf16_t* h1  = w2b + nw2;

  cvt3_kernel<<<dim3(4096), dim3(256), 0, stream>>>(
      x, xb, nx / 8, W1, w1b, nw1 / 8, W2, w2b, nw2 / 8);

  // GEMM1: M=2048, N=4096(INTER), K=1024(HIDDEN) -> h1 (bf16)
  // m-inner: 64 resident blocks/XCD span full per-group A (4.2 MB, L2-resident)
  gemm_bt<MTOK, INTER, HIDDEN, true, true>
      <<<dim3(NUM_GEMMS * (MTOK / 128) * (INTER / 128)), dim3(256), 0, stream>>>(
          xb, w1b, b1, (void*)h1);

  // GEMM2: M=2048, N=1024(HIDDEN), K=4096(INTER) -> out (fp32)
  // n-inner: 8 consecutive blocks share one 1 MB h1 A-tile
  gemm_bt<MTOK, HIDDEN, INTER, false, false>
      <<<dim3(NUM_GEMMS * (MTOK / 128) * (HIDDEN / 128)), dim3(256), 0, stream>>>(
          h1, w2b, b2, (void*)out);
}